// Round 6
// baseline (35548.926 us; speedup 1.0000x reference)
//
#include <hip/hip_runtime.h>
#include <stdint.h>

#define B_ 256
#define T_ 512
#define D_ 128
#define H_ 256

typedef __attribute__((ext_vector_type(8))) _Float16 half8;
typedef __attribute__((ext_vector_type(4))) float f32x4;
typedef __attribute__((ext_vector_type(4))) int i32x4;

// ws layout (bytes)
#define WS_PART 0                      // 16*256 floats fc partials
#define WS_H0   65536                  // [2][256][256] u32 (epoch<<16 | f16) layer0 h
#define WS_H1   (WS_H0 + 2*B_*H_*4)    // [2][256][256] u32 layer1 h

__device__ __forceinline__ float fast_sig(float x) {
    return 1.0f / (1.0f + __expf(-x));
}
__device__ __forceinline__ float fast_tanh(float x) {
    float xc = fminf(fmaxf(x, -30.0f), 30.0f);
    float e = __expf(-2.0f * xc);
    return (1.0f - e) / (1.0f + e);
}
__device__ __forceinline__ half8 cvt8(const float* p) {
    const f32x4* q = (const f32x4*)p;
    f32x4 a = q[0], b = q[1];
    half8 r;
    r[0] = (_Float16)a[0]; r[1] = (_Float16)a[1];
    r[2] = (_Float16)a[2]; r[3] = (_Float16)a[3];
    r[4] = (_Float16)b[0]; r[5] = (_Float16)b[1];
    r[6] = (_Float16)b[2]; r[7] = (_Float16)b[3];
    return r;
}
__device__ __forceinline__ half8 cvt8v(f32x4 a, f32x4 b) {
    half8 r;
    r[0] = (_Float16)a[0]; r[1] = (_Float16)a[1];
    r[2] = (_Float16)a[2]; r[3] = (_Float16)a[3];
    r[4] = (_Float16)b[0]; r[5] = (_Float16)b[1];
    r[6] = (_Float16)b[2]; r[7] = (_Float16)b[3];
    return r;
}

// LDS-only barrier (verified round 3): __syncthreads' implicit vmcnt(0) would
// drain our in-flight MALL traffic; these barriers only guard LDS.
__device__ __forceinline__ void bar_lds() {
    asm volatile("s_waitcnt lgkmcnt(0)" ::: "memory");
    __builtin_amdgcn_s_barrier();
}

// ---- sc0 (XCD-local L2) primitives — FAST path, verified correct round 5 ----
__device__ __forceinline__ void poll4f_issue(const unsigned* p, i32x4* r) {
    asm volatile(
        "global_load_dwordx4 %0, %4, off sc0\n\t"
        "global_load_dwordx4 %1, %4, off offset:16 sc0\n\t"
        "global_load_dwordx4 %2, %4, off offset:128 sc0\n\t"
        "global_load_dwordx4 %3, %4, off offset:144 sc0"
        : "=&v"(r[0]), "=&v"(r[1]), "=&v"(r[2]), "=&v"(r[3])
        : "v"(p) : "memory");
}
__device__ __forceinline__ void poll4f_wait(const unsigned* p, i32x4* r) {
    asm volatile(
        "global_load_dwordx4 %0, %4, off sc0\n\t"
        "global_load_dwordx4 %1, %4, off offset:16 sc0\n\t"
        "global_load_dwordx4 %2, %4, off offset:128 sc0\n\t"
        "global_load_dwordx4 %3, %4, off offset:144 sc0\n\t"
        "s_waitcnt vmcnt(0)"
        : "=&v"(r[0]), "=&v"(r[1]), "=&v"(r[2]), "=&v"(r[3])
        : "v"(p) : "memory");
}
__device__ __forceinline__ void store_dw_l2(unsigned* p, unsigned v) {
    asm volatile("global_store_dword %0, %1, off sc0" :: "v"(p), "v"(v) : "memory");
}

// ---- sc0 sc1 (MALL) primitives — authoritative fallback path ----
__device__ __forceinline__ void poll4_wait(const unsigned* p, i32x4* r) {
    asm volatile(
        "global_load_dwordx4 %0, %4, off sc0 sc1\n\t"
        "global_load_dwordx4 %1, %4, off offset:16 sc0 sc1\n\t"
        "global_load_dwordx4 %2, %4, off offset:128 sc0 sc1\n\t"
        "global_load_dwordx4 %3, %4, off offset:144 sc0 sc1\n\t"
        "s_waitcnt vmcnt(0)"
        : "=&v"(r[0]), "=&v"(r[1]), "=&v"(r[2]), "=&v"(r[3])
        : "v"(p) : "memory");
}
__device__ __forceinline__ void store_dw_mall(unsigned* p, unsigned v) {
    asm volatile("global_store_dword %0, %1, off sc0 sc1" :: "v"(p), "v"(v) : "memory");
}

// Entry wait: COUNTED vmcnt(2). Per-iteration VM issue order is
//   xr(8) -> fast-st(2) -> polls(8) -> [xacc vmcnt(0)] -> mall-st(2),
// so "<=2 outstanding" proves the 8 polls complete while the 2 MALL store
// acks (the newest ops) may still be in flight -> acks are NEVER waited.
// Safety net: if data is stale/torn for any reason, the epoch tags fail and
// the self-draining re-poll loop recovers — correctness does not depend on
// this wait being sufficient.
__device__ __forceinline__ void wait_tie8_vm2(i32x4* a, i32x4* b) {
    asm volatile("s_waitcnt vmcnt(2)"
        : "+v"(a[0]), "+v"(a[1]), "+v"(a[2]), "+v"(a[3]),
          "+v"(b[0]), "+v"(b[1]), "+v"(b[2]), "+v"(b[3]) :: "memory");
}

__device__ __forceinline__ int tags_ok(const i32x4* r, unsigned tag) {
    unsigned m = 0;
#pragma unroll
    for (int i = 0; i < 4; ++i) {
        m |= ((unsigned)r[i][0] ^ tag); m |= ((unsigned)r[i][1] ^ tag);
        m |= ((unsigned)r[i][2] ^ tag); m |= ((unsigned)r[i][3] ^ tag);
    }
    return __all((m & 0xFFFF0000u) == 0);
}
// unpack 4-tile snapshot payloads -> LDS rows (wave's 2 k-tiles)
__device__ __forceinline__ void unpack_to_lds(const i32x4* r, _Float16* base) {
#pragma unroll
    for (int t = 0; t < 2; ++t) {
        i32x4 pk;
        pk[0] = (r[2 * t][0] & 0xFFFF) | (r[2 * t][1] << 16);
        pk[1] = (r[2 * t][2] & 0xFFFF) | (r[2 * t][3] << 16);
        pk[2] = (r[2 * t + 1][0] & 0xFFFF) | (r[2 * t + 1][1] << 16);
        pk[3] = (r[2 * t + 1][2] & 0xFFFF) | (r[2 * t + 1][3] << 16);
        *(i32x4*)(base + t * 32) = pk;
    }
}

// grid 256 wgs x 256 thr. wg = (batch group g = blk&15) x (hidden slice sl = blk>>4)
// wave w = gate (i,f,g,o); weights pinned in regs as f16 MFMA B-frags.
// Layer-pipelined: iter u does layer0 step u (u<T) and layer1 step u-1 (u>=1).
// h exchange: SINGLE buffer per layer, stored TWICE — early sc0 store (lands in
// the shared XCD L2; round-robin placement co-locates each group on one XCD,
// verified round 5) and a DEFERRED sc0 sc1 MALL store at the iteration tail
// (authoritative, covers stragglers). Entry uses a counted vmcnt(2) so the
// MALL store-acks are never on the critical path (the round-2/3/5 evidence
// says the ack drain was the invariant ~µs/step cost).
__global__ __launch_bounds__(256, 1) void lstm_main(
    const float* __restrict__ x, const int* __restrict__ mask,
    const float* __restrict__ Wih0, const float* __restrict__ Whh0,
    const float* __restrict__ bih0, const float* __restrict__ bhh0,
    const float* __restrict__ Wih1, const float* __restrict__ Whh1,
    const float* __restrict__ bih1, const float* __restrict__ bhh1,
    const float* __restrict__ fcw, char* __restrict__ ws)
{
    const int tid  = threadIdx.x;
    const int blk  = blockIdx.x;
    const int g    = blk & 15;    // batch group
    const int sl   = blk >> 4;    // hidden slice
    const int b0   = g * 16;
    const int j0   = sl * 16;
    const int w    = tid >> 6;
    const int lane = tid & 63;
    const int row  = lane & 15;
    const int quad = lane >> 4;
    const int kb   = quad * 8;

    float*    partials = (float*)(ws + WS_PART);
    unsigned* h0u      = (unsigned*)(ws + WS_H0);
    unsigned* h1u      = (unsigned*)(ws + WS_H1);

    __shared__ float gbuf[2048];
    __shared__ __align__(16) _Float16 hsh0[16 * 264];
    __shared__ __align__(16) _Float16 hsh1[16 * 264];

    // ---- pin weights in registers (f16 B-frags), n = gate row ----
    const int n = w * H_ + j0 + row;
    half8 wA[12], wB[16];
#pragma unroll
    for (int kt = 0; kt < 4; ++kt) wA[kt]     = cvt8(&Wih0[(size_t)n * D_ + kt * 32 + kb]);
#pragma unroll
    for (int kt = 0; kt < 8; ++kt) wA[4 + kt] = cvt8(&Whh0[(size_t)n * H_ + kt * 32 + kb]);
#pragma unroll
    for (int kt = 0; kt < 8; ++kt) wB[kt]     = cvt8(&Wih1[(size_t)n * H_ + kt * 32 + kb]);
#pragma unroll
    for (int kt = 0; kt < 8; ++kt) wB[8 + kt] = cvt8(&Whh1[(size_t)n * H_ + kt * 32 + kb]);
    const float biasA = bih0[n] + bhh0[n];
    const float biasB = bih1[n] + bhh1[n];

    const int bb    = tid >> 4;
    const int jj    = tid & 15;
    const int bglob = b0 + bb;

    int len = 0;
    {
        const int* mrow = mask + (size_t)bglob * T_ + jj * 32;
#pragma unroll
        for (int q = 0; q < 32; ++q) len += mrow[q];
#pragma unroll
        for (int o = 1; o < 16; o <<= 1) len += __shfl_xor(len, o, 16);
    }

    float c0 = 0.f, c1 = 0.f, hsave = 0.f;

    const float* xrow = x + (size_t)(b0 + row) * T_ * D_ + kb;
    // xacc for step 0 (plain loads, consumed pre-loop)
    f32x4 xacc = {0.f, 0.f, 0.f, 0.f};
#pragma unroll
    for (int kt = 0; kt < 4; ++kt)
        xacc = __builtin_amdgcn_mfma_f32_16x16x32_f16(cvt8(xrow + kt * 32), wA[kt], xacc, 0, 0, 0);

    i32x4 r0[4], r1[4];   // pre-issued h0 / h1 snapshots
    const int koff = w * 64 + quad * 8;  // this wave's k-quarter (u32 units)

    for (int u = 0; u <= T_; ++u) {
        half8 a0[8], a1[8];
        f32x4 xr[8];
        int h1ok = 1;
        const unsigned tag1 = (unsigned)(u - 1) << 16;
        const size_t off1 = ((size_t)(u & 1) * B_ + (b0 + row)) * H_ + koff;
        unsigned pv0 = 0, pv1 = 0;           // deferred MALL store payloads
        size_t   so0 = 0, so1 = 0;           // and addresses

        if (u >= 1) {
            // ---- step entry: COUNTED wait (polls done, MALL acks unwaited) ----
            wait_tie8_vm2(r0, r1);
            const unsigned tag0 = (unsigned)u << 16;
            const size_t off0 = ((size_t)((u - 1) & 1) * B_ + (b0 + row)) * H_ + koff;
            {
                int guard = 0;
                while (!tags_ok(r0, tag0)) {       // alternate fast/MALL re-poll
                    if (guard & 1) poll4_wait(h0u + off0, r0);
                    else           poll4f_wait(h0u + off0, r0);
                    if (++guard > (1 << 16)) break;  // bounded: fail loud, never hang
                }
            }
            h1ok = (u >= 2) ? tags_ok(r1, tag1) : 1;
            // x prefetch for u+1 (plain cached loads)
            {
                const int tn = (u + 1 < T_) ? (u + 1) : (T_ - 1);
                const f32x4* q = (const f32x4*)(xrow + (size_t)tn * D_);
#pragma unroll
                for (int kt = 0; kt < 4; ++kt) { xr[2 * kt] = q[kt * 8]; xr[2 * kt + 1] = q[kt * 8 + 1]; }
            }
            // unpack h0 -> LDS, share across waves, read A-frags
            unpack_to_lds(r0, hsh0 + row * 264 + koff);
            bar_lds();  // sync A (LDS-only)
#pragma unroll
            for (int kt = 0; kt < 8; ++kt)
                a0[kt] = *(const half8*)(hsh0 + row * 264 + kt * 32 + quad * 8);
        } else {
            const f32x4* q = (const f32x4*)(xrow + (size_t)1 * D_);
#pragma unroll
            for (int kt = 0; kt < 4; ++kt) { xr[2 * kt] = q[kt * 8]; xr[2 * kt + 1] = q[kt * 8 + 1]; }
        }

        // ================= layer 0 (critical recurrence) =================
        if (u < T_) {
            f32x4 acc0 = xacc;
            if (u >= 1) {
#pragma unroll
                for (int kt = 0; kt < 8; ++kt)
                    acc0 = __builtin_amdgcn_mfma_f32_16x16x32_f16(a0[kt], wA[4 + kt], acc0, 0, 0, 0);
            }
#pragma unroll
            for (int r = 0; r < 4; ++r)
                gbuf[w * 256 + (quad * 4 + r) * 16 + row] = acc0[r] + biasA;
            bar_lds();  // sync B (LDS-only)
            const int idx = bb * 16 + jj;
            float gi = fast_sig(gbuf[idx]);
            float gf = fast_sig(gbuf[256 + idx]);
            float gg = fast_tanh(gbuf[512 + idx]);
            float go = fast_sig(gbuf[768 + idx]);
            c0 = gf * c0 + gi * gg;
            float h0v = go * fast_tanh(c0);
            union { _Float16 h; unsigned short s; } cv; cv.h = (_Float16)h0v;
            pv0 = ((unsigned)(u + 1) << 16) | cv.s;
            so0 = ((size_t)(u & 1) * B_ + bglob) * H_ + j0 + jj;
            store_dw_l2(h0u + so0, pv0);   // EARLY sc0 store: peers (same XCD L2) see it now
        }
        __builtin_amdgcn_sched_barrier(0);  // keep layer1 below the h0 store

        // ================= layer 1 (one step of slack) =================
        if (u >= 1) {
            f32x4 acc1 = {0.f, 0.f, 0.f, 0.f};
#pragma unroll
            for (int kt = 0; kt < 8; ++kt)
                acc1 = __builtin_amdgcn_mfma_f32_16x16x32_f16(a0[kt], wB[kt], acc1, 0, 0, 0);
            if (u >= 2) {
                if (!h1ok) {
                    int guard = 0;
                    while (!h1ok) {                // alternate fast/MALL re-poll
                        if (guard & 1) poll4_wait(h1u + off1, r1);
                        else           poll4f_wait(h1u + off1, r1);
                        h1ok = tags_ok(r1, tag1);
                        if (++guard > (1 << 16)) break;
                    }
                }
                unpack_to_lds(r1, hsh1 + row * 264 + koff);
                bar_lds();  // sync C (LDS-only)
#pragma unroll
                for (int kt = 0; kt < 8; ++kt)
                    a1[kt] = *(const half8*)(hsh1 + row * 264 + kt * 32 + quad * 8);
#pragma unroll
                for (int kt = 0; kt < 8; ++kt)
                    acc1 = __builtin_amdgcn_mfma_f32_16x16x32_f16(a1[kt], wB[8 + kt], acc1, 0, 0, 0);
            }
#pragma unroll
            for (int r = 0; r < 4; ++r)
                gbuf[1024 + w * 256 + (quad * 4 + r) * 16 + row] = acc1[r] + biasB;
            bar_lds();  // sync D (LDS-only)
            const int idx = bb * 16 + jj;
            float gi = fast_sig(gbuf[1024 + idx]);
            float gf = fast_sig(gbuf[1024 + 256 + idx]);
            float gg = fast_tanh(gbuf[1024 + 512 + idx]);
            float go = fast_sig(gbuf[1024 + 768 + idx]);
            c1 = gf * c1 + gi * gg;
            float h1v = go * fast_tanh(c1);
            union { _Float16 h; unsigned short s; } cv; cv.h = (_Float16)h1v;
            pv1 = ((unsigned)u << 16) | cv.s;
            so1 = ((size_t)((u - 1) & 1) * B_ + bglob) * H_ + j0 + jj;
            store_dw_l2(h1u + so1, pv1);   // EARLY sc0 store
            if (u == len) hsave = h1v;
        }

        // ---- pre-issue next step's FAST snapshots (fire-and-forget) ----
        if (u < T_) {
            const int v = u + 1;
            const unsigned* q0 = h0u + ((size_t)((v - 1) & 1) * B_ + (b0 + row)) * H_ + koff;
            const unsigned* q1 = (v >= 2)
                ? h1u + ((size_t)(v & 1) * B_ + (b0 + row)) * H_ + koff
                : q0;
            poll4f_issue(q0, r0);
            poll4f_issue(q1, r1);
        }

        // xacc for step u+1 (compiler inserts vmcnt(0): drains only the cheap
        // L2 fast-store acks + just-issued L2 polls — no MALL traffic yet)
        if (u < T_ - 1) {
            f32x4 t = {0.f, 0.f, 0.f, 0.f};
#pragma unroll
            for (int kt = 0; kt < 4; ++kt)
                t = __builtin_amdgcn_mfma_f32_16x16x32_f16(cvt8v(xr[2 * kt], xr[2 * kt + 1]), wA[kt], t, 0, 0, 0);
            xacc = t;
        }

        // ---- DEFERRED authoritative MALL stores: LAST in the VM queue, so
        // the next entry's vmcnt(2) never waits their acks ----
        if (u < T_) {
            store_dw_mall(h0u + so0, pv0);
            if (u >= 1) store_dw_mall(h1u + so1, pv1);
            else        store_dw_mall(h0u + so0, pv0);  // dup: uniform depth-2
        }
    }

    float part = hsave * fcw[j0 + jj];
#pragma unroll
    for (int o = 1; o < 16; o <<= 1) part += __shfl_xor(part, o, 16);
    if (jj == 0) partials[sl * B_ + bglob] = part;
}

__global__ void lstm_fc(const float* __restrict__ fcb, const char* __restrict__ ws,
                        float* __restrict__ out) {
    const int b = threadIdx.x;
    const float* partials = (const float*)(ws + WS_PART);
    float s = fcb[0];
#pragma unroll
    for (int sl = 0; sl < 16; ++sl) s += partials[sl * B_ + b];
    out[b] = s;
}

extern "C" void kernel_launch(void* const* d_in, const int* in_sizes, int n_in,
                              void* d_out, int out_size, void* d_ws, size_t ws_size,
                              hipStream_t stream) {
    const float* xx    = (const float*)d_in[0];
    const int*   mask  = (const int*)d_in[1];
    const float* Wih0  = (const float*)d_in[2];
    const float* Whh0  = (const float*)d_in[3];
    const float* bih0  = (const float*)d_in[4];
    const float* bhh0  = (const float*)d_in[5];
    const float* Wih1  = (const float*)d_in[6];
    const float* Whh1  = (const float*)d_in[7];
    const float* bih1  = (const float*)d_in[8];
    const float* bhh1  = (const float*)d_in[9];
    const float* fcw   = (const float*)d_in[10];
    const float* fcb   = (const float*)d_in[11];

    lstm_main<<<dim3(256), dim3(256), 0, stream>>>(
        xx, mask, Wih0, Whh0, bih0, bhh0, Wih1, Whh1, bih1, bhh1, fcw, (char*)d_ws);
    lstm_fc<<<dim3(1), dim3(256), 0, stream>>>(fcb, (const char*)d_ws, (float*)d_out);
}

// Round 7
// 1760.487 us; speedup vs baseline: 20.1927x; 20.1927x over previous
//
#include <hip/hip_runtime.h>
#include <stdint.h>

#define B_ 256
#define T_ 512
#define D_ 128
#define H_ 256

typedef __attribute__((ext_vector_type(8))) _Float16 half8;
typedef __attribute__((ext_vector_type(4))) float f32x4;
typedef __attribute__((ext_vector_type(4))) int i32x4;

// ws layout (bytes)
#define WS_PART 0                      // 16*256 floats fc partials
#define WS_H0   65536                  // [2][256][256] u32 (epoch<<16 | f16) layer0 h  (MALL, authoritative)
#define WS_H1   (WS_H0 + 2*B_*H_*4)    // [2][256][256] u32 layer1 h                    (MALL, authoritative)
#define WS_F0   (WS_H1 + 2*B_*H_*4)    // fast mirror of WS_H0 (sc0-only, XCD-local L2)
#define WS_F1   (WS_F0 + 2*B_*H_*4)    // fast mirror of WS_H1
// NOTE (round 6 lesson): mirrors and authoritative buffers MUST be disjoint
// lines — mixing sc0 and sc0sc1 stores on the same line forces a writeback/
// invalidate storm (20x slowdown, WRITE_SIZE doubled).

__device__ __forceinline__ float fast_sig(float x) {
    return 1.0f / (1.0f + __expf(-x));
}
__device__ __forceinline__ float fast_tanh(float x) {
    float xc = fminf(fmaxf(x, -30.0f), 30.0f);
    float e = __expf(-2.0f * xc);
    return (1.0f - e) / (1.0f + e);
}
__device__ __forceinline__ half8 cvt8(const float* p) {
    const f32x4* q = (const f32x4*)p;
    f32x4 a = q[0], b = q[1];
    half8 r;
    r[0] = (_Float16)a[0]; r[1] = (_Float16)a[1];
    r[2] = (_Float16)a[2]; r[3] = (_Float16)a[3];
    r[4] = (_Float16)b[0]; r[5] = (_Float16)b[1];
    r[6] = (_Float16)b[2]; r[7] = (_Float16)b[3];
    return r;
}
__device__ __forceinline__ half8 cvt8v(f32x4 a, f32x4 b) {
    half8 r;
    r[0] = (_Float16)a[0]; r[1] = (_Float16)a[1];
    r[2] = (_Float16)a[2]; r[3] = (_Float16)a[3];
    r[4] = (_Float16)b[0]; r[5] = (_Float16)b[1];
    r[6] = (_Float16)b[2]; r[7] = (_Float16)b[3];
    return r;
}

// LDS-only barrier (verified round 3): __syncthreads' implicit vmcnt(0) would
// drain our in-flight MALL traffic; these barriers only guard LDS.
__device__ __forceinline__ void bar_lds() {
    asm volatile("s_waitcnt lgkmcnt(0)" ::: "memory");
    __builtin_amdgcn_s_barrier();
}

// ---- sc0 (XCD-local L2) primitives — FAST path, verified correct round 5 ----
__device__ __forceinline__ void poll4f_issue(const unsigned* p, i32x4* r) {
    asm volatile(
        "global_load_dwordx4 %0, %4, off sc0\n\t"
        "global_load_dwordx4 %1, %4, off offset:16 sc0\n\t"
        "global_load_dwordx4 %2, %4, off offset:128 sc0\n\t"
        "global_load_dwordx4 %3, %4, off offset:144 sc0"
        : "=&v"(r[0]), "=&v"(r[1]), "=&v"(r[2]), "=&v"(r[3])
        : "v"(p) : "memory");
}
__device__ __forceinline__ void poll4f_wait(const unsigned* p, i32x4* r) {
    asm volatile(
        "global_load_dwordx4 %0, %4, off sc0\n\t"
        "global_load_dwordx4 %1, %4, off offset:16 sc0\n\t"
        "global_load_dwordx4 %2, %4, off offset:128 sc0\n\t"
        "global_load_dwordx4 %3, %4, off offset:144 sc0\n\t"
        "s_waitcnt vmcnt(0)"
        : "=&v"(r[0]), "=&v"(r[1]), "=&v"(r[2]), "=&v"(r[3])
        : "v"(p) : "memory");
}
__device__ __forceinline__ void store_dw_l2(unsigned* p, unsigned v) {
    asm volatile("global_store_dword %0, %1, off sc0" :: "v"(p), "v"(v) : "memory");
}

// ---- sc0 sc1 (MALL) primitives — authoritative path ----
__device__ __forceinline__ void poll4_wait(const unsigned* p, i32x4* r) {
    asm volatile(
        "global_load_dwordx4 %0, %4, off sc0 sc1\n\t"
        "global_load_dwordx4 %1, %4, off offset:16 sc0 sc1\n\t"
        "global_load_dwordx4 %2, %4, off offset:128 sc0 sc1\n\t"
        "global_load_dwordx4 %3, %4, off offset:144 sc0 sc1\n\t"
        "s_waitcnt vmcnt(0)"
        : "=&v"(r[0]), "=&v"(r[1]), "=&v"(r[2]), "=&v"(r[3])
        : "v"(p) : "memory");
}
__device__ __forceinline__ void store_dw_mall(unsigned* p, unsigned v) {
    asm volatile("global_store_dword %0, %1, off sc0 sc1" :: "v"(p), "v"(v) : "memory");
}

// Entry wait: COUNTED vmcnt(2). The per-iteration VM queue ends with the 2
// deferred MALL stores as the NEWEST ops, and the xacc block's compiler
// vmcnt(0) has already drained everything older (fast polls, mirror acks).
// So "<=2 outstanding" proves the pre-issued polls are complete while the
// MALL store-acks are never waited. Safety net: consumption is tag-gated and
// the re-poll loops self-drain — a miscount costs a spin, not correctness.
__device__ __forceinline__ void wait_tie8_vm2(i32x4* a, i32x4* b) {
    asm volatile("s_waitcnt vmcnt(2)"
        : "+v"(a[0]), "+v"(a[1]), "+v"(a[2]), "+v"(a[3]),
          "+v"(b[0]), "+v"(b[1]), "+v"(b[2]), "+v"(b[3]) :: "memory");
}

__device__ __forceinline__ int tags_ok(const i32x4* r, unsigned tag) {
    unsigned m = 0;
#pragma unroll
    for (int i = 0; i < 4; ++i) {
        m |= ((unsigned)r[i][0] ^ tag); m |= ((unsigned)r[i][1] ^ tag);
        m |= ((unsigned)r[i][2] ^ tag); m |= ((unsigned)r[i][3] ^ tag);
    }
    return __all((m & 0xFFFF0000u) == 0);
}
// unpack 4-tile snapshot payloads -> LDS rows (wave's 2 k-tiles)
__device__ __forceinline__ void unpack_to_lds(const i32x4* r, _Float16* base) {
#pragma unroll
    for (int t = 0; t < 2; ++t) {
        i32x4 pk;
        pk[0] = (r[2 * t][0] & 0xFFFF) | (r[2 * t][1] << 16);
        pk[1] = (r[2 * t][2] & 0xFFFF) | (r[2 * t][3] << 16);
        pk[2] = (r[2 * t + 1][0] & 0xFFFF) | (r[2 * t + 1][1] << 16);
        pk[3] = (r[2 * t + 1][2] & 0xFFFF) | (r[2 * t + 1][3] << 16);
        *(i32x4*)(base + t * 32) = pk;
    }
}

// grid 256 wgs x 256 thr. wg = (batch group g = blk&15) x (hidden slice sl = blk>>4)
// wave w = gate (i,f,g,o); weights pinned in regs as f16 MFMA B-frags.
// Layer-pipelined: iter u does layer0 step u (u<T) and layer1 step u-1 (u>=1).
// h exchange (round-5 protocol + deferred authoritative stores):
//   - EARLY sc0 store to the L2 mirror (f0u/f1u): peers on the same XCD (the
//     common case under round-robin placement, verified round 5) read it with
//     ~L2 latency via pre-issued sc0 polls.
//   - DEFERRED sc0 sc1 store to the authoritative buffer (h0u/h1u), issued
//     LAST in the iteration's VM queue so its ack is NEVER waited (entry uses
//     counted vmcnt(2)). Cross-XCD stragglers fall back to tag-gated MALL
//     re-polls against it (one-step lag, provably deadlock-free).
__global__ __launch_bounds__(256, 1) void lstm_main(
    const float* __restrict__ x, const int* __restrict__ mask,
    const float* __restrict__ Wih0, const float* __restrict__ Whh0,
    const float* __restrict__ bih0, const float* __restrict__ bhh0,
    const float* __restrict__ Wih1, const float* __restrict__ Whh1,
    const float* __restrict__ bih1, const float* __restrict__ bhh1,
    const float* __restrict__ fcw, char* __restrict__ ws)
{
    const int tid  = threadIdx.x;
    const int blk  = blockIdx.x;
    const int g    = blk & 15;    // batch group
    const int sl   = blk >> 4;    // hidden slice
    const int b0   = g * 16;
    const int j0   = sl * 16;
    const int w    = tid >> 6;
    const int lane = tid & 63;
    const int row  = lane & 15;
    const int quad = lane >> 4;
    const int kb   = quad * 8;

    float*    partials = (float*)(ws + WS_PART);
    unsigned* h0u      = (unsigned*)(ws + WS_H0);
    unsigned* h1u      = (unsigned*)(ws + WS_H1);
    unsigned* f0u      = (unsigned*)(ws + WS_F0);
    unsigned* f1u      = (unsigned*)(ws + WS_F1);

    __shared__ float gbuf[2048];
    __shared__ __align__(16) _Float16 hsh0[16 * 264];
    __shared__ __align__(16) _Float16 hsh1[16 * 264];

    // ---- pin weights in registers (f16 B-frags), n = gate row ----
    const int n = w * H_ + j0 + row;
    half8 wA[12], wB[16];
#pragma unroll
    for (int kt = 0; kt < 4; ++kt) wA[kt]     = cvt8(&Wih0[(size_t)n * D_ + kt * 32 + kb]);
#pragma unroll
    for (int kt = 0; kt < 8; ++kt) wA[4 + kt] = cvt8(&Whh0[(size_t)n * H_ + kt * 32 + kb]);
#pragma unroll
    for (int kt = 0; kt < 8; ++kt) wB[kt]     = cvt8(&Wih1[(size_t)n * H_ + kt * 32 + kb]);
#pragma unroll
    for (int kt = 0; kt < 8; ++kt) wB[8 + kt] = cvt8(&Whh1[(size_t)n * H_ + kt * 32 + kb]);
    const float biasA = bih0[n] + bhh0[n];
    const float biasB = bih1[n] + bhh1[n];

    const int bb    = tid >> 4;
    const int jj    = tid & 15;
    const int bglob = b0 + bb;

    int len = 0;
    {
        const int* mrow = mask + (size_t)bglob * T_ + jj * 32;
#pragma unroll
        for (int q = 0; q < 32; ++q) len += mrow[q];
#pragma unroll
        for (int o = 1; o < 16; o <<= 1) len += __shfl_xor(len, o, 16);
    }

    float c0 = 0.f, c1 = 0.f, hsave = 0.f;

    const float* xrow = x + (size_t)(b0 + row) * T_ * D_ + kb;
    // xacc for step 0 (plain loads, consumed pre-loop)
    f32x4 xacc = {0.f, 0.f, 0.f, 0.f};
#pragma unroll
    for (int kt = 0; kt < 4; ++kt)
        xacc = __builtin_amdgcn_mfma_f32_16x16x32_f16(cvt8(xrow + kt * 32), wA[kt], xacc, 0, 0, 0);

    i32x4 r0[4], r1[4];   // pre-issued h0 / h1 snapshots (from the L2 mirrors)
    const int koff = w * 64 + quad * 8;  // this wave's k-quarter (u32 units)

    for (int u = 0; u <= T_; ++u) {
        half8 a0[8], a1[8];
        f32x4 xr[8];
        int h1ok = 1;
        const unsigned tag1 = (unsigned)(u - 1) << 16;
        const size_t off1 = ((size_t)(u & 1) * B_ + (b0 + row)) * H_ + koff;
        unsigned pv0 = 0, pv1 = 0;           // deferred MALL store payloads
        size_t   so0 = 0, so1 = 0;           // and offsets

        if (u >= 1) {
            // ---- step entry: COUNTED wait (polls done, MALL acks unwaited) ----
            wait_tie8_vm2(r0, r1);
            const unsigned tag0 = (unsigned)u << 16;
            const size_t off0 = ((size_t)((u - 1) & 1) * B_ + (b0 + row)) * H_ + koff;
            if (!tags_ok(r0, tag0)) {
                poll4f_wait(f0u + off0, r0);           // fast retry (local L2 mirror)
                int guard = 0;
                while (!tags_ok(r0, tag0)) {           // authoritative MALL loop
                    poll4_wait(h0u + off0, r0);
                    if (++guard > (1 << 16)) break;    // bounded: fail loud, never hang
                }
            }
            h1ok = (u >= 2) ? tags_ok(r1, tag1) : 1;
            // x prefetch for u+1 (plain cached loads)
            {
                const int tn = (u + 1 < T_) ? (u + 1) : (T_ - 1);
                const f32x4* q = (const f32x4*)(xrow + (size_t)tn * D_);
#pragma unroll
                for (int kt = 0; kt < 4; ++kt) { xr[2 * kt] = q[kt * 8]; xr[2 * kt + 1] = q[kt * 8 + 1]; }
            }
            // unpack h0 -> LDS, share across waves, read A-frags
            unpack_to_lds(r0, hsh0 + row * 264 + koff);
            bar_lds();  // sync A (LDS-only)
#pragma unroll
            for (int kt = 0; kt < 8; ++kt)
                a0[kt] = *(const half8*)(hsh0 + row * 264 + kt * 32 + quad * 8);
        } else {
            const f32x4* q = (const f32x4*)(xrow + (size_t)1 * D_);
#pragma unroll
            for (int kt = 0; kt < 4; ++kt) { xr[2 * kt] = q[kt * 8]; xr[2 * kt + 1] = q[kt * 8 + 1]; }
        }

        // ================= layer 0 (critical recurrence) =================
        if (u < T_) {
            f32x4 acc0 = xacc;
            if (u >= 1) {
#pragma unroll
                for (int kt = 0; kt < 8; ++kt)
                    acc0 = __builtin_amdgcn_mfma_f32_16x16x32_f16(a0[kt], wA[4 + kt], acc0, 0, 0, 0);
            }
#pragma unroll
            for (int r = 0; r < 4; ++r)
                gbuf[w * 256 + (quad * 4 + r) * 16 + row] = acc0[r] + biasA;
            bar_lds();  // sync B (LDS-only)
            const int idx = bb * 16 + jj;
            float gi = fast_sig(gbuf[idx]);
            float gf = fast_sig(gbuf[256 + idx]);
            float gg = fast_tanh(gbuf[512 + idx]);
            float go = fast_sig(gbuf[768 + idx]);
            c0 = gf * c0 + gi * gg;
            float h0v = go * fast_tanh(c0);
            union { _Float16 h; unsigned short s; } cv; cv.h = (_Float16)h0v;
            pv0 = ((unsigned)(u + 1) << 16) | cv.s;
            so0 = ((size_t)(u & 1) * B_ + bglob) * H_ + j0 + jj;
            store_dw_l2(f0u + so0, pv0);   // EARLY mirror store: same-XCD peers see it now
        }
        __builtin_amdgcn_sched_barrier(0);  // keep layer1 below the h0 mirror store

        // ================= layer 1 (one step of slack) =================
        if (u >= 1) {
            f32x4 acc1 = {0.f, 0.f, 0.f, 0.f};
#pragma unroll
            for (int kt = 0; kt < 8; ++kt)
                acc1 = __builtin_amdgcn_mfma_f32_16x16x32_f16(a0[kt], wB[kt], acc1, 0, 0, 0);
            if (u >= 2) {
                if (!h1ok) {
                    poll4f_wait(f1u + off1, r1);       // fast retry (local L2 mirror)
                    h1ok = tags_ok(r1, tag1);
                    int guard = 0;
                    while (!h1ok) {                    // authoritative MALL loop
                        poll4_wait(h1u + off1, r1);
                        h1ok = tags_ok(r1, tag1);
                        if (++guard > (1 << 16)) break;
                    }
                }
                unpack_to_lds(r1, hsh1 + row * 264 + koff);
                bar_lds();  // sync C (LDS-only)
#pragma unroll
                for (int kt = 0; kt < 8; ++kt)
                    a1[kt] = *(const half8*)(hsh1 + row * 264 + kt * 32 + quad * 8);
#pragma unroll
                for (int kt = 0; kt < 8; ++kt)
                    acc1 = __builtin_amdgcn_mfma_f32_16x16x32_f16(a1[kt], wB[8 + kt], acc1, 0, 0, 0);
            }
#pragma unroll
            for (int r = 0; r < 4; ++r)
                gbuf[1024 + w * 256 + (quad * 4 + r) * 16 + row] = acc1[r] + biasB;
            bar_lds();  // sync D (LDS-only)
            const int idx = bb * 16 + jj;
            float gi = fast_sig(gbuf[1024 + idx]);
            float gf = fast_sig(gbuf[1024 + 256 + idx]);
            float gg = fast_tanh(gbuf[1024 + 512 + idx]);
            float go = fast_sig(gbuf[1024 + 768 + idx]);
            c1 = gf * c1 + gi * gg;
            float h1v = go * fast_tanh(c1);
            union { _Float16 h; unsigned short s; } cv; cv.h = (_Float16)h1v;
            pv1 = ((unsigned)u << 16) | cv.s;
            so1 = ((size_t)((u - 1) & 1) * B_ + bglob) * H_ + j0 + jj;
            store_dw_l2(f1u + so1, pv1);   // EARLY mirror store
            if (u == len) hsave = h1v;
        }

        // ---- pre-issue next step's FAST snapshots (fire-and-forget) ----
        if (u < T_) {
            const int v = u + 1;
            const unsigned* q0 = f0u + ((size_t)((v - 1) & 1) * B_ + (b0 + row)) * H_ + koff;
            const unsigned* q1 = (v >= 2)
                ? f1u + ((size_t)(v & 1) * B_ + (b0 + row)) * H_ + koff
                : q0;
            poll4f_issue(q0, r0);
            poll4f_issue(q1, r1);
        }

        // xacc for step u+1 (compiler inserts vmcnt(0): at this point only
        // L2-cheap ops are outstanding — mirror-store acks + fast polls)
        if (u < T_ - 1) {
            f32x4 t = {0.f, 0.f, 0.f, 0.f};
#pragma unroll
            for (int kt = 0; kt < 4; ++kt)
                t = __builtin_amdgcn_mfma_f32_16x16x32_f16(cvt8v(xr[2 * kt], xr[2 * kt + 1]), wA[kt], t, 0, 0, 0);
            xacc = t;
        }
        __builtin_amdgcn_sched_barrier(0);  // pin the deferred stores BELOW xacc's drain

        // ---- DEFERRED authoritative MALL stores: newest ops in the queue,
        // so the next entry's vmcnt(2) never waits their acks ----
        if (u < T_)  store_dw_mall(h0u + so0, pv0);
        if (u >= 1)  store_dw_mall(h1u + so1, pv1);
    }

    float part = hsave * fcw[j0 + jj];
#pragma unroll
    for (int o = 1; o < 16; o <<= 1) part += __shfl_xor(part, o, 16);
    if (jj == 0) partials[sl * B_ + bglob] = part;
}

__global__ void lstm_fc(const float* __restrict__ fcb, const char* __restrict__ ws,
                        float* __restrict__ out) {
    const int b = threadIdx.x;
    const float* partials = (const float*)(ws + WS_PART);
    float s = fcb[0];
#pragma unroll
    for (int sl = 0; sl < 16; ++sl) s += partials[sl * B_ + b];
    out[b] = s;
}

extern "C" void kernel_launch(void* const* d_in, const int* in_sizes, int n_in,
                              void* d_out, int out_size, void* d_ws, size_t ws_size,
                              hipStream_t stream) {
    const float* xx    = (const float*)d_in[0];
    const int*   mask  = (const int*)d_in[1];
    const float* Wih0  = (const float*)d_in[2];
    const float* Whh0  = (const float*)d_in[3];
    const float* bih0  = (const float*)d_in[4];
    const float* bhh0  = (const float*)d_in[5];
    const float* Wih1  = (const float*)d_in[6];
    const float* Whh1  = (const float*)d_in[7];
    const float* bih1  = (const float*)d_in[8];
    const float* bhh1  = (const float*)d_in[9];
    const float* fcw   = (const float*)d_in[10];
    const float* fcb   = (const float*)d_in[11];

    lstm_main<<<dim3(256), dim3(256), 0, stream>>>(
        xx, mask, Wih0, Whh0, bih0, bhh0, Wih1, Whh1, bih1, bhh1, fcw, (char*)d_ws);
    lstm_fc<<<dim3(1), dim3(256), 0, stream>>>(fcb, (const char*)d_ws, (float*)d_out);
}